// Round 1
// baseline (38.800 us; speedup 1.0000x reference)
//
#include <hip/hip_runtime.h>

#define IMG 256
#define NB 64
#define NCH 8
#define NROWS (NB * IMG)   // 16384 (b,h) rows
#define PLANE (IMG * IMG)  // 65536

// Kernel 1: per (b,h) row, find the contiguous masked interval.
// mask(b,h,w)  <=>  (2w-255)^2 + (2h-255)^2 < sizes[b]^2   (exact integer test,
// provably equivalent to the reference's f32 sqrt comparison).
__global__ void count_rows(const int* __restrict__ sizes,
                           int* __restrict__ counts,
                           int* __restrict__ wlo) {
    int idx = blockIdx.x * blockDim.x + threadIdx.x;
    if (idx >= NROWS) return;
    int b = idx >> 8;
    int h = idx & 255;
    int s = sizes[b];
    int s2 = s * s;
    int ky = 2 * h - 255;
    int rem = s2 - ky * ky;
    int lo = 256;  // sentinel: empty row
    if (rem > 0) {
        // smallest w in [0,127] with (255-2w)^2 < rem; kx^2 decreasing in w
        for (int w = 0; w < 128; ++w) {
            int kx = 255 - 2 * w;
            if (kx * kx < rem) { lo = w; break; }
        }
    }
    // symmetric interval [lo, 255-lo]
    int cnt = (lo < 256) ? (256 - 2 * lo) : 0;
    counts[idx] = cnt;
    wlo[idx] = lo;
}

// Kernel 2: single-block exclusive prefix sum of 16384 row counts.
// Also writes the trailing batch_size scalar.
__global__ void scan_rows(const int* __restrict__ counts,
                          int* __restrict__ offsets,
                          float* __restrict__ out, int out_size) {
    __shared__ int part[256];
    int t = threadIdx.x;
    int base = t * 64;
    int s = 0;
    for (int i = 0; i < 64; ++i) s += counts[base + i];
    part[t] = s;
    __syncthreads();
    // Hillis-Steele inclusive scan over 256 partials
    for (int d = 1; d < 256; d <<= 1) {
        int v = (t >= d) ? part[t - d] : 0;
        __syncthreads();
        part[t] += v;
        __syncthreads();
    }
    int run = (t == 0) ? 0 : part[t - 1];
    for (int i = 0; i < 64; ++i) {
        offsets[base + i] = run;
        run += counts[base + i];
    }
    if (t == 0) out[out_size - 1] = (float)NB;  // batch_size = 64
}

// Kernel 3: one block per (b,h) row, thread = w. Masked threads write
// tex (8 f32, two float4), pts (float2: y=h, x=w), imgid (float b).
__global__ void scatter_rows(const float* __restrict__ batch,
                             const int* __restrict__ offsets,
                             const int* __restrict__ wlo,
                             const int* __restrict__ counts,
                             float* __restrict__ out, int N) {
    int row = blockIdx.x;
    int w = threadIdx.x;
    int lo = wlo[row];
    int cnt = counts[row];
    if (w < lo || w >= lo + cnt) return;
    int off = offsets[row];
    int b = row >> 8;
    int h = row & 255;
    int n = off + (w - lo);

    const float* bp = batch + (size_t)b * NCH * PLANE + h * IMG + w;
    float4 t0, t1;
    t0.x = bp[0 * PLANE]; t0.y = bp[1 * PLANE];
    t0.z = bp[2 * PLANE]; t0.w = bp[3 * PLANE];
    t1.x = bp[4 * PLANE]; t1.y = bp[5 * PLANE];
    t1.z = bp[6 * PLANE]; t1.w = bp[7 * PLANE];

    float4* texp = (float4*)(out + (size_t)n * 8);  // n*8 -> 32B aligned
    texp[0] = t0;
    texp[1] = t1;

    float2* ptsp = (float2*)(out + (size_t)N * 8 + (size_t)n * 2);
    *ptsp = make_float2((float)h, (float)w);  // (y, x)

    out[(size_t)N * 10 + n] = (float)b;
}

extern "C" void kernel_launch(void* const* d_in, const int* in_sizes, int n_in,
                              void* d_out, int out_size, void* d_ws, size_t ws_size,
                              hipStream_t stream) {
    const float* batch = (const float*)d_in[0];
    const int* sizes = (const int*)d_in[1];
    float* out = (float*)d_out;

    // out layout: tex [N*8] | pts [N*2] | imgid [N] | batch_size [1]
    int N = (out_size - 1) / 11;

    int* counts  = (int*)d_ws;           // 16384 ints
    int* offsets = counts + NROWS;       // 16384 ints
    int* wlo     = offsets + NROWS;      // 16384 ints

    count_rows<<<NROWS / 256, 256, 0, stream>>>(sizes, counts, wlo);
    scan_rows<<<1, 256, 0, stream>>>(counts, offsets, out, out_size);
    scatter_rows<<<NROWS, 256, 0, stream>>>(batch, offsets, wlo, counts, out, N);
}

// Round 2
// 31.020 us; speedup vs baseline: 1.2508x; 1.2508x over previous
//
#include <hip/hip_runtime.h>

#define IMG 256
#define NB 64
#define NCH 8
#define NROWS (NB * IMG)   // 16384 (b,h) rows
#define PLANE (IMG * IMG)  // 65536

// floor(sqrt(x)) for 0 <= x <= 65535, exact via f32 sqrt + correction
__device__ __forceinline__ int isqrt_i(int x) {
    int t = (int)__builtin_sqrtf((float)x);
    t -= (t * t > x);
    t += ((t + 1) * (t + 1) <= x);
    return t;
}

// Closed-form row interval. mask(b,h,w) <=> (2w-255)^2 + (2h-255)^2 < s^2.
// Returns cnt; lo = (255 - (cnt-1)) / 2 since cnt = kx_max+1, interval symmetric.
__device__ __forceinline__ int row_count(int s, int h) {
    int ky = 2 * h - 255;
    int rem = s * s - ky * ky;
    if (rem < 2) return 0;           // kx^2 >= 1 for all w, need kx^2 < rem
    int t = isqrt_i(rem - 1);        // largest t with t^2 < rem
    int kx_max = (t & 1) ? t : t - 1;  // kx = 255-2w is odd
    return kx_max + 1;               // even count; lo = (255 - kx_max)/2
}

// Kernel A: one block per image b, thread = h. Compute cnt analytically,
// exclusive LDS scan over the 256 rows -> within-image row offsets + image total.
__global__ void scan_image(const int* __restrict__ sizes,
                           int* __restrict__ rowoff,
                           int* __restrict__ totals) {
    __shared__ int sh[IMG];
    int b = blockIdx.x;
    int h = threadIdx.x;
    int s = sizes[b];
    int cnt = row_count(s, h);
    sh[h] = cnt;
    __syncthreads();
    // Hillis-Steele inclusive scan over 256
    for (int d = 1; d < IMG; d <<= 1) {
        int v = (h >= d) ? sh[h - d] : 0;
        __syncthreads();
        sh[h] += v;
        __syncthreads();
    }
    rowoff[b * IMG + h] = sh[h] - cnt;   // exclusive
    if (h == IMG - 1) totals[b] = sh[h];
}

// Kernel B: scan the 64 image totals -> image base offsets; write batch_size.
__global__ void scan_totals(const int* __restrict__ totals,
                            int* __restrict__ image_base,
                            float* __restrict__ out, int out_size) {
    __shared__ int sh[NB];
    int t = threadIdx.x;
    sh[t] = totals[t];
    __syncthreads();
    for (int d = 1; d < NB; d <<= 1) {
        int v = (t >= d) ? sh[t - d] : 0;
        __syncthreads();
        sh[t] += v;
        __syncthreads();
    }
    image_base[t] = sh[t] - totals[t];   // exclusive
    if (t == 0) out[out_size - 1] = (float)NB;  // batch_size = 64
}

// Kernel C: one block per (b,h) row, thread = w. Interval recomputed in closed
// form (uniform per block). Masked threads write tex (two float4), pts, imgid.
__global__ void scatter_rows(const float* __restrict__ batch,
                             const int* __restrict__ sizes,
                             const int* __restrict__ rowoff,
                             const int* __restrict__ image_base,
                             float* __restrict__ out, int N) {
    int row = blockIdx.x;
    int b = row >> 8;
    int h = row & 255;
    int w = threadIdx.x;
    int s = sizes[b];
    int cnt = row_count(s, h);
    if (cnt == 0) return;
    int lo = (255 - (cnt - 1)) >> 1;
    if (w < lo || w >= lo + cnt) return;
    int n = image_base[b] + rowoff[row] + (w - lo);

    const float* bp = batch + (size_t)b * NCH * PLANE + h * IMG + w;
    float4 t0, t1;
    t0.x = bp[0 * PLANE]; t0.y = bp[1 * PLANE];
    t0.z = bp[2 * PLANE]; t0.w = bp[3 * PLANE];
    t1.x = bp[4 * PLANE]; t1.y = bp[5 * PLANE];
    t1.z = bp[6 * PLANE]; t1.w = bp[7 * PLANE];

    float4* texp = (float4*)(out + (size_t)n * 8);  // n*8 floats -> 32B aligned
    texp[0] = t0;
    texp[1] = t1;

    float2* ptsp = (float2*)(out + (size_t)N * 8 + (size_t)n * 2);
    *ptsp = make_float2((float)h, (float)w);  // (y, x)

    out[(size_t)N * 10 + n] = (float)b;
}

extern "C" void kernel_launch(void* const* d_in, const int* in_sizes, int n_in,
                              void* d_out, int out_size, void* d_ws, size_t ws_size,
                              hipStream_t stream) {
    const float* batch = (const float*)d_in[0];
    const int* sizes = (const int*)d_in[1];
    float* out = (float*)d_out;

    // out layout: tex [N*8] | pts [N*2] | imgid [N] | batch_size [1]
    int N = (out_size - 1) / 11;

    int* rowoff     = (int*)d_ws;          // 16384 ints
    int* totals     = rowoff + NROWS;      // 64 ints
    int* image_base = totals + NB;         // 64 ints

    scan_image<<<NB, IMG, 0, stream>>>(sizes, rowoff, totals);
    scan_totals<<<1, NB, 0, stream>>>(totals, image_base, out, out_size);
    scatter_rows<<<NROWS, 256, 0, stream>>>(batch, sizes, rowoff, image_base, out, N);
}

// Round 3
// 30.173 us; speedup vs baseline: 1.2859x; 1.0281x over previous
//
#include <hip/hip_runtime.h>

#define IMG 256
#define NB 64
#define NCH 8
#define NROWS (NB * IMG)   // 16384 (b,h) rows
#define PLANE (IMG * IMG)  // 65536

// floor(sqrt(x)) for 0 <= x <= 65535, exact via f32 sqrt + +/-1 correction
__device__ __forceinline__ int isqrt_i(int x) {
    int t = (int)__builtin_sqrtf((float)x);
    t -= (t * t > x);
    t += ((t + 1) * (t + 1) <= x);
    return t;
}

// Closed-form row interval count. mask(b,h,w) <=> (2w-255)^2 + (2h-255)^2 < s^2
// (exact integer equivalence with the reference's f32 sqrt comparison).
// cnt is even; interval is [lo, 255-lo] with lo = (255 - (cnt-1))/2.
__device__ __forceinline__ int row_count(int s, int h) {
    int ky = 2 * h - 255;
    int rem = s * s - ky * ky;
    if (rem < 2) return 0;             // need kx^2 < rem with kx odd >= 1
    int t = isqrt_i(rem - 1);          // largest t with t^2 < rem
    int kx_max = (t & 1) ? t : t - 1;  // kx = 255-2w is odd
    return kx_max + 1;
}

// Kernel S: single block, 1024 threads. Per-image areas via LDS accumulation,
// then one wave scans the 64 totals -> image_base. Also writes batch_size.
__global__ void setup_kernel(const int* __restrict__ sizes,
                             int* __restrict__ image_base,
                             float* __restrict__ out, int out_size) {
    __shared__ int acc[NB];
    __shared__ int s_sz[NB];
    int t = threadIdx.x;  // 0..1023
    if (t < NB) { acc[t] = 0; s_sz[t] = sizes[t]; }
    __syncthreads();
    // 16384 (b,h) pairs, 16 consecutive h per thread (never crosses an image)
    int b = t >> 4;
    int s = s_sz[b];
    int h0 = (t & 15) * 16;
    int sum = 0;
    #pragma unroll
    for (int k = 0; k < 16; ++k) sum += row_count(s, h0 + k);
    atomicAdd(&acc[b], sum);
    __syncthreads();
    if (t < NB) {
        int a = acc[t];
        int v = a;
        // inclusive wave scan over 64 lanes
        for (int d = 1; d < 64; d <<= 1) {
            int u = __shfl_up(v, d);
            if (t >= d) v += u;
        }
        image_base[t] = v - a;  // exclusive
    }
    if (t == 0) out[out_size - 1] = (float)NB;  // batch_size = 64
}

// Kernel C: one block per (b,h) row, thread = w. Row offset computed in-block:
// thread t contributes row_count(s, t) for t < h, shuffle-reduced. Masked
// threads then write tex (two float4), pts (float2), imgid.
__global__ void scatter_rows(const float* __restrict__ batch,
                             const int* __restrict__ sizes,
                             const int* __restrict__ image_base,
                             float* __restrict__ out, int N) {
    int row = blockIdx.x;
    int b = row >> 8;
    int h = row & 255;
    int t = threadIdx.x;
    int s = sizes[b];                 // uniform scalar load
    int cnt = row_count(s, h);        // uniform
    if (cnt == 0) return;             // uniform exit, ~38% of rows

    // sum_{h'<h} row_count(s,h') via per-thread eval + block reduce
    int c = (t < h) ? row_count(s, t) : 0;
    for (int o = 32; o; o >>= 1) c += __shfl_down(c, o);
    __shared__ int wsum[4];
    __shared__ int s_n0;
    if ((t & 63) == 0) wsum[t >> 6] = c;
    __syncthreads();
    if (t == 0) s_n0 = image_base[b] + wsum[0] + wsum[1] + wsum[2] + wsum[3];
    __syncthreads();

    int lo = (255 - (cnt - 1)) >> 1;
    if (t < lo || t >= lo + cnt) return;
    int n = s_n0 + (t - lo);

    const float* bp = batch + (size_t)b * NCH * PLANE + h * IMG + t;
    float4 t0, t1;
    t0.x = bp[0 * PLANE]; t0.y = bp[1 * PLANE];
    t0.z = bp[2 * PLANE]; t0.w = bp[3 * PLANE];
    t1.x = bp[4 * PLANE]; t1.y = bp[5 * PLANE];
    t1.z = bp[6 * PLANE]; t1.w = bp[7 * PLANE];

    float4* texp = (float4*)(out + (size_t)n * 8);  // 32B-aligned
    texp[0] = t0;
    texp[1] = t1;

    float2* ptsp = (float2*)(out + (size_t)N * 8 + (size_t)n * 2);
    *ptsp = make_float2((float)h, (float)t);  // (y, x)

    out[(size_t)N * 10 + n] = (float)b;
}

extern "C" void kernel_launch(void* const* d_in, const int* in_sizes, int n_in,
                              void* d_out, int out_size, void* d_ws, size_t ws_size,
                              hipStream_t stream) {
    const float* batch = (const float*)d_in[0];
    const int* sizes = (const int*)d_in[1];
    float* out = (float*)d_out;

    // out layout: tex [N*8] | pts [N*2] | imgid [N] | batch_size [1]
    int N = (out_size - 1) / 11;

    int* image_base = (int*)d_ws;  // 64 ints

    setup_kernel<<<1, 1024, 0, stream>>>(sizes, image_base, out, out_size);
    scatter_rows<<<NROWS, 256, 0, stream>>>(batch, sizes, image_base, out, N);
}